// Round 11
// baseline (216.382 us; speedup 1.0000x reference)
//
#include <hip/hip_runtime.h>
#include <math.h>

#define N_NODES 20000
#define N_EDGESC 320000
#define ET (N_EDGESC + N_NODES)   // 340000 incl. self-loops
#define F_IN 128
#define H1 512
#define H2 256
#define N_CLS 40
#define NEG_SLOPE 0.2f
#define DEGMAX 64                 // slot capacity; overflow list handles deg>64

typedef __attribute__((ext_vector_type(8))) short short8;
typedef __attribute__((ext_vector_type(4))) float floatx4;

__device__ __forceinline__ unsigned short f2bf(float x) {
    unsigned u = __float_as_uint(x);
    unsigned r = (u + 0x7fffu + ((u >> 16) & 1u)) >> 16;  // RNE
    return (unsigned short)r;
}
__device__ __forceinline__ float bflo(unsigned v) { return __uint_as_float(v << 16); }
__device__ __forceinline__ float bfhi(unsigned v) { return __uint_as_float(v & 0xffff0000u); }
__device__ __forceinline__ float leaky(float e) { return (e > 0.f) ? e : e * NEG_SLOPE; }

// ---------------- shared device bodies -------------------------------------

// wa GEMV: one wave computes wab entries for one W row. row in [0,896).
__device__ __forceinline__ void wa_row(int row, int lane,
        const float* __restrict__ W1, const float* __restrict__ a1s, const float* __restrict__ a1d,
        const float* __restrict__ W2, const float* __restrict__ a2s, const float* __restrict__ a2d,
        const float* __restrict__ W3, const float* __restrict__ a3s, const float* __restrict__ a3d,
        float* __restrict__ wab) {
    const float *W, *vs, *vd;
    float *os, *od;
    int N, k;
    if (row < 128)      { k = row;       W = W1; vs = a1s; vd = a1d; os = wab;        od = wab + 128;  N = H1; }
    else if (row < 640) { k = row - 128; W = W2; vs = a2s; vd = a2d; os = wab + 256;  od = wab + 768;  N = H2; }
    else                { k = row - 640; W = W3; vs = a3s; vd = a3d; os = wab + 1280; od = wab + 1536; N = N_CLS; }
    const float* r = W + (size_t)k * N;
    float ss = 0.f, sd = 0.f;
    for (int n = lane; n < N; n += 64) {
        float v = r[n];
        ss += v * vs[n];
        sd += v * vd[n];
    }
    #pragma unroll
    for (int off = 32; off; off >>= 1) {
        ss += __shfl_xor(ss, off);
        sd += __shfl_xor(sd, off);
    }
    if (lane == 0) { os[k] = ss; od[k] = sd; }
}

// W -> W^T bf16, flat element index i over all three matrices
#define NCT (F_IN * H1 + H1 * H2 + H2 * N_CLS)  // 206848
__device__ __forceinline__ void castT_el(int i,
        const float* __restrict__ W1, unsigned short* __restrict__ w1t,
        const float* __restrict__ W2, unsigned short* __restrict__ w2t,
        const float* __restrict__ W3, unsigned short* __restrict__ w3t) {
    if (i < F_IN * H1) {
        int k = i >> 9, n = i & 511;
        w1t[n * F_IN + k] = f2bf(W1[i]);
    } else if (i < F_IN * H1 + H1 * H2) {
        int j = i - F_IN * H1;
        int k = j >> 8, n = j & 255;
        w2t[n * H1 + k] = f2bf(W2[j]);
    } else if (i < NCT) {
        int j = i - (F_IN * H1 + H1 * H2);
        int k = j / N_CLS, n = j - k * N_CLS;
        w3t[n * H2 + k] = f2bf(W3[j]);
    }
}

// gemv: als[i]=in[i,:].wvs, ald[i]=in[i,:].wvd
template <int DIN, bool IN_BF16>
__device__ __forceinline__ void gemv2_body(int node, int lane, const void* __restrict__ in,
                                           const float* __restrict__ wvs,
                                           const float* __restrict__ wvd,
                                           float* __restrict__ als, float* __restrict__ ald) {
    constexpr int C = DIN / 64;
    float ss = 0.f, sd = 0.f;
    if constexpr (IN_BF16) {
        const unsigned short* r = (const unsigned short*)in + (size_t)node * DIN + lane * C;
        float f[C];
        if constexpr (C == 8) {
            uint4 v = *(const uint4*)r;
            f[0] = bflo(v.x); f[1] = bfhi(v.x); f[2] = bflo(v.y); f[3] = bfhi(v.y);
            f[4] = bflo(v.z); f[5] = bfhi(v.z); f[6] = bflo(v.w); f[7] = bfhi(v.w);
        } else {
            uint2 v = *(const uint2*)r;
            f[0] = bflo(v.x); f[1] = bfhi(v.x); f[2] = bflo(v.y); f[3] = bfhi(v.y);
        }
        #pragma unroll
        for (int c = 0; c < C; ++c) {
            ss += f[c] * wvs[lane * C + c];
            sd += f[c] * wvd[lane * C + c];
        }
    } else {
        const float* r = (const float*)in + (size_t)node * DIN + lane * 2;
        float2 v = *(const float2*)r;
        ss = v.x * wvs[lane * 2] + v.y * wvs[lane * 2 + 1];
        sd = v.x * wvd[lane * 2] + v.y * wvd[lane * 2 + 1];
    }
    #pragma unroll
    for (int off = 32; off; off >>= 1) {
        ss += __shfl_xor(ss, off);
        sd += __shfl_xor(sd, off);
    }
    if (lane == 0) { als[node] = ss; ald[node] = sd; }
}

// softmax-attention aggregation body. SPLIT waves cooperate on one node,
// each covering DOUT/SPLIT columns (softmax weights recomputed per wave).
template <int DOUT, int SPLIT, bool BIAS, bool RELU, bool LSM, bool IN_BF16, bool OUT_BF16>
__device__ __forceinline__ void agg_body(int wid, int lane,
        const void* __restrict__ h, const float* __restrict__ as, const float* __restrict__ ad,
        const int* __restrict__ deg, const int* __restrict__ csr_src,
        const int* __restrict__ ocnt, const int* __restrict__ oflow,
        const float* __restrict__ bias, void* __restrict__ outp) {
    constexpr int CD = DOUT / SPLIT;      // cols per wave
    constexpr int C = (CD + 63) / 64;     // cols per lane
    int node = wid / SPLIT;
    int colbase = (SPLIT == 1) ? 0 : (wid % SPLIT) * CD;
    if (node >= N_NODES) return;
    int degt = deg[node];
    int cnt = min(degt, DEGMAX);
    int base = node << 6;
    float adi = ad[node];
    bool ovf = degt > DEGMAX;          // ~never
    int novf = ovf ? *ocnt : 0;

    bool has0 = lane < cnt;
    int sj = has0 ? csr_src[base + lane] : 0;
    float ej = has0 ? leaky(as[sj] + adi) : -INFINITY;

    float m = ej;
    if (ovf) {
        for (int i = lane; i < novf; i += 64)
            if (oflow[2 * i] == node) m = fmaxf(m, leaky(as[oflow[2 * i + 1]] + adi));
    }
    #pragma unroll
    for (int off = 32; off; off >>= 1) m = fmaxf(m, __shfl_xor(m, off));

    float den = has0 ? expf(ej - m) : 0.f;
    if (ovf) {
        for (int i = lane; i < novf; i += 64)
            if (oflow[2 * i] == node) den += expf(leaky(as[oflow[2 * i + 1]] + adi) - m);
    }
    #pragma unroll
    for (int off = 32; off; off >>= 1) den += __shfl_xor(den, off);
    float invden = 1.f / den;

    float wgt = has0 ? expf(ej - m) * invden : 0.f;

    float acc[C];
    #pragma unroll
    for (int c = 0; c < C; ++c) acc[c] = 0.f;

    auto fetch = [&](int s, float* f) {
        if constexpr (IN_BF16) {
            const unsigned short* hr = (const unsigned short*)h + (size_t)s * DOUT + colbase + lane * C;
            if constexpr (C == 8) {
                uint4 v = *(const uint4*)hr;
                f[0] = bflo(v.x); f[1] = bfhi(v.x); f[2] = bflo(v.y); f[3] = bfhi(v.y);
                f[4] = bflo(v.z); f[5] = bfhi(v.z); f[6] = bflo(v.w); f[7] = bfhi(v.w);
            } else if constexpr (C == 4) {
                uint2 v = *(const uint2*)hr;
                f[0] = bflo(v.x); f[1] = bfhi(v.x); f[2] = bflo(v.y); f[3] = bfhi(v.y);
            } else {
                unsigned v = *(const unsigned*)hr;
                f[0] = bflo(v); f[1] = bfhi(v);
            }
        } else {
            if (lane < CD) f[0] = ((const float*)h)[(size_t)s * DOUT + colbase + lane];
            else f[0] = 0.f;
        }
    };

    int j = 0;
    for (; j + 7 < cnt; j += 8) {
        int s[8]; float a[8]; float f[8][C];
        #pragma unroll
        for (int u = 0; u < 8; ++u) { s[u] = __shfl(sj, j + u); a[u] = __shfl(wgt, j + u); }
        #pragma unroll
        for (int u = 0; u < 8; ++u) fetch(s[u], f[u]);
        #pragma unroll
        for (int u = 0; u < 8; ++u)
            #pragma unroll
            for (int c = 0; c < C; ++c) acc[c] += a[u] * f[u][c];
    }
    for (; j < cnt; ++j) {
        int s0 = __shfl(sj, j);
        float a0 = __shfl(wgt, j);
        float f0[C];
        fetch(s0, f0);
        #pragma unroll
        for (int c = 0; c < C; ++c) acc[c] += a0 * f0[c];
    }
    if (ovf) {  // wave-uniform scan of the (tiny) overflow list
        for (int i = 0; i < novf; ++i) {
            if (oflow[2 * i] == node) {
                int s0 = oflow[2 * i + 1];
                float a0 = expf(leaky(as[s0] + adi) - m) * invden;
                float f0[C];
                fetch(s0, f0);
                #pragma unroll
                for (int c = 0; c < C; ++c) acc[c] += a0 * f0[c];
            }
        }
    }

    if constexpr (!LSM) {
        #pragma unroll
        for (int c = 0; c < C; ++c) {
            int col = colbase + lane * C + c;
            if (CD % 64 == 0 || lane * C + c < CD) {
                float v = acc[c];
                if constexpr (BIAS) v += bias[col];
                if constexpr (RELU) v = fmaxf(v, 0.f);
                if constexpr (OUT_BF16)
                    ((unsigned short*)outp)[(size_t)node * DOUT + col] = f2bf(v);
                else
                    ((float*)outp)[(size_t)node * DOUT + col] = v;
            }
        }
    } else {
        float v = (lane < DOUT) ? (acc[0] + bias[lane]) : -INFINITY;
        float mm = v;
        #pragma unroll
        for (int off = 32; off; off >>= 1) mm = fmaxf(mm, __shfl_xor(mm, off));
        float ex = (lane < DOUT) ? expf(v - mm) : 0.f;
        float Z = ex;
        #pragma unroll
        for (int off = 32; off; off >>= 1) Z += __shfl_xor(Z, off);
        if (lane < DOUT) ((float*)outp)[(size_t)node * DOUT + lane] = v - mm - logf(Z);
    }
}

// ---------------- stage 1: minimal critical prep ---------------------------
#define PZ ((N_NODES + 1 + 255) / 256)   // 79: deg + ocnt
#define PW1 32                            // wa rows 0..127

__global__ __launch_bounds__(256) void prep0_kernel(
        const float* __restrict__ W1, const float* __restrict__ a1s, const float* __restrict__ a1d,
        const float* __restrict__ W2, const float* __restrict__ a2s, const float* __restrict__ a2d,
        const float* __restrict__ W3, const float* __restrict__ a3s, const float* __restrict__ a3d,
        float* __restrict__ wab, int* __restrict__ deg, int* __restrict__ ocnt) {
    int bid = blockIdx.x, t = threadIdx.x;
    if (bid < PZ) {
        int i = bid * 256 + t;
        if (i < N_NODES) deg[i] = 0;
        else if (i == N_NODES) *ocnt = 0;
    } else {
        int row = (bid - PZ) * 4 + (t >> 6);  // 0..127
        if (row < 128) wa_row(row, t & 63, W1, a1s, a1d, W2, a2s, a2d, W3, a3s, a3d, wab);
    }
}

// ---------------- stage 2: bucket-CSR fill + castX + gemv-L1 ---------------
#define CB_CNT ((ET + 255) / 256)  // 1329
#define CXB 2500                   // castX blocks
#define NODEB ((N_NODES + 3) / 4)  // 5000

__global__ __launch_bounds__(256) void fill_castx_gemv1_kernel(
        const int* __restrict__ ei, int* __restrict__ deg,
        int* __restrict__ csr_src, int* __restrict__ ocnt, int* __restrict__ oflow,
        const float* __restrict__ x, unsigned short* __restrict__ xb,
        const float* __restrict__ wab, float* __restrict__ als1, float* __restrict__ ald1) {
    int bid = blockIdx.x, t = threadIdx.x;
    if (bid < CB_CNT) {
        int e = bid * 256 + t;
        if (e < ET) {
            int s, d;
            if (e < N_EDGESC) { s = ei[e]; d = ei[N_EDGESC + e]; }
            else { s = d = e - N_EDGESC; }
            int slot = atomicAdd(&deg[d], 1);
            if (slot < DEGMAX) csr_src[(d << 6) + slot] = s;
            else {
                int o = atomicAdd(ocnt, 1);
                oflow[2 * o] = d;
                oflow[2 * o + 1] = s;
            }
        }
    } else if (bid < CB_CNT + CXB) {
        int i = ((bid - CB_CNT) * 256 + t) * 4;
        float4 v = *(const float4*)(x + i);
        ushort4 o = { f2bf(v.x), f2bf(v.y), f2bf(v.z), f2bf(v.w) };
        *(ushort4*)(xb + i) = o;
    } else {
        int node = (bid - CB_CNT - CXB) * 4 + (t >> 6);
        if (node < N_NODES)
            gemv2_body<F_IN, false>(node, t & 63, x, wab, wab + 128, als1, ald1);
    }
}

// ---------------- stage 3: agg-L1 + castT-all + wa rows 128..895 -----------
#define CTB ((NCT + 255) / 256)    // 808

__global__ __launch_bounds__(256) void agg1_tails_kernel(
        const unsigned short* __restrict__ xb,
        const float* __restrict__ als1, const float* __restrict__ ald1,
        const int* __restrict__ deg, const int* __restrict__ csr_src,
        const int* __restrict__ ocnt, const int* __restrict__ oflow,
        unsigned short* __restrict__ zb,
        const float* __restrict__ W1, unsigned short* __restrict__ w1t,
        const float* __restrict__ W2, unsigned short* __restrict__ w2t,
        const float* __restrict__ W3, unsigned short* __restrict__ w3t,
        const float* __restrict__ a1s, const float* __restrict__ a1d,
        const float* __restrict__ a2s, const float* __restrict__ a2d,
        const float* __restrict__ a3s, const float* __restrict__ a3d,
        float* __restrict__ wab) {
    int bid = blockIdx.x, t = threadIdx.x;
    if (bid < NODEB) {
        agg_body<F_IN, 1, false, false, false, true, true>(
            bid * 4 + (t >> 6), t & 63, xb, als1, ald1, deg, csr_src, ocnt, oflow, nullptr, zb);
    } else if (bid < NODEB + CTB) {
        castT_el((bid - NODEB) * 256 + t, W1, w1t, W2, w2t, W3, w3t);
    } else {
        int row = 128 + (bid - NODEB - CTB) * 4 + (t >> 6);  // 128..895
        if (row < 896) wa_row(row, t & 63, W1, a1s, a1d, W2, a2s, a2d, W3, a3s, a3d, wab);
    }
}

// ---------------- MFMA GEMM (1D grid) + optional tail gemv -----------------
#define LDT 40   // padded LDS stride (bf16) per 32-wide k tile
#define LSO 66   // epilogue repack stride (bf16)

template <int MT, int NT, bool BIASRELU, bool OUT_BF16, int GDIN, bool GBF16>
__global__ __launch_bounds__(256) void gemm_fused(
        const unsigned short* __restrict__ A, const unsigned short* __restrict__ Bt,
        void* __restrict__ Cp, const float* __restrict__ bias,
        int M, int K, int N, int gemm_blocks,
        const void* __restrict__ gin, const float* __restrict__ wvs,
        const float* __restrict__ wvd, float* __restrict__ als, float* __restrict__ ald) {
    constexpr int MI = MT / 64;
    __shared__ unsigned short As[MT * LDT];
    __shared__ unsigned short Bs[64 * LDT];
    __shared__ unsigned short Ls[64 * LSO];
    int bid = blockIdx.x, t = threadIdx.x;
    int w = t >> 6, lane = t & 63;

    if (bid >= gemm_blocks) {
        if constexpr (GDIN > 0) {
            int node = (bid - gemm_blocks) * 4 + w;
            if (node < N_NODES)
                gemv2_body<GDIN, GBF16>(node, lane, gin, wvs, wvd, als, ald);
        }
        return;
    }

    int quad = lane >> 4, l16 = lane & 15;
    int bm = (bid / NT) * MT, bn = (bid % NT) * 64;
    int ar0 = t >> 2;
    int ak = (t & 3) * 8;

    floatx4 acc[MI][4];
    #pragma unroll
    for (int i = 0; i < MI; ++i)
        #pragma unroll
        for (int j = 0; j < 4; ++j) acc[i][j] = (floatx4){0.f, 0.f, 0.f, 0.f};

    uint4 pa0 = {0,0,0,0}, pa1 = {0,0,0,0}, pb = {0,0,0,0};
    {
        int gm0 = bm + ar0, gn = bn + ar0;
        if (gm0 < M) pa0 = *(const uint4*)(A + (size_t)gm0 * K + ak);
        if constexpr (MI == 2) {
            int gm1 = bm + 64 + ar0;
            if (gm1 < M) pa1 = *(const uint4*)(A + (size_t)gm1 * K + ak);
        }
        if (gn < N) pb = *(const uint4*)(Bt + (size_t)gn * K + ak);
    }

    for (int k0 = 0; k0 < K; k0 += 32) {
        *(uint4*)(&As[ar0 * LDT + ak]) = pa0;
        if constexpr (MI == 2) *(uint4*)(&As[(64 + ar0) * LDT + ak]) = pa1;
        *(uint4*)(&Bs[ar0 * LDT + ak]) = pb;
        __syncthreads();

        int kn = k0 + 32;
        if (kn < K) {
            int gm0 = bm + ar0, gn = bn + ar0;
            pa0 = (gm0 < M) ? *(const uint4*)(A + (size_t)gm0 * K + kn + ak) : (uint4){0,0,0,0};
            if constexpr (MI == 2) {
                int gm1 = bm + 64 + ar0;
                pa1 = (gm1 < M) ? *(const uint4*)(A + (size_t)gm1 * K + kn + ak) : (uint4){0,0,0,0};
            }
            pb = (gn < N) ? *(const uint4*)(Bt + (size_t)gn * K + kn + ak) : (uint4){0,0,0,0};
        }

        short8 a[MI], b[4];
        #pragma unroll
        for (int mi = 0; mi < MI; ++mi)
            a[mi] = *(short8*)(&As[(w * (MT / 4) + mi * 16 + l16) * LDT + quad * 8]);
        #pragma unroll
        for (int ni = 0; ni < 4; ++ni)
            b[ni] = *(short8*)(&Bs[(ni * 16 + l16) * LDT + quad * 8]);
        #pragma unroll
        for (int mi = 0; mi < MI; ++mi)
            #pragma unroll
            for (int ni = 0; ni < 4; ++ni)
                acc[mi][ni] = __builtin_amdgcn_mfma_f32_16x16x32_bf16(a[mi], b[ni], acc[mi][ni], 0, 0, 0);
        __syncthreads();
    }

    if constexpr (OUT_BF16) {
        #pragma unroll
        for (int mi = 0; mi < MI; ++mi) {
            #pragma unroll
            for (int ni = 0; ni < 4; ++ni) {
                int col = bn + ni * 16 + l16;
                #pragma unroll
                for (int r = 0; r < 4; ++r) {
                    float v = acc[mi][ni][r];
                    if constexpr (BIASRELU) v = fmaxf(v + bias[col], 0.f);
                    Ls[(w * 16 + quad * 4 + r) * LSO + ni * 16 + l16] = f2bf(v);
                }
            }
            __syncthreads();
            #pragma unroll
            for (int i = 0; i < 2; ++i) {
                int idx = t + i * 256;
                int lrow = idx >> 3, c8 = (idx & 7) * 8;
                int grow = bm + (lrow >> 4) * (MT / 4) + mi * 16 + (lrow & 15);
                if (grow < M)
                    *(uint4*)((unsigned short*)Cp + (size_t)grow * N + bn + c8) =
                        *(uint4*)(&Ls[lrow * LSO + c8]);
            }
            __syncthreads();
        }
    } else {
        #pragma unroll
        for (int mi = 0; mi < MI; ++mi) {
            #pragma unroll
            for (int r = 0; r < 4; ++r) {
                int row = bm + w * (MT / 4) + mi * 16 + quad * 4 + r;
                if (row >= M) continue;
                #pragma unroll
                for (int ni = 0; ni < 4; ++ni) {
                    int col = bn + ni * 16 + l16;
                    if (col < N) ((float*)Cp)[(size_t)row * N + col] = acc[mi][ni][r];
                }
            }
        }
    }
}

// ---------------- agg wrapper kernels --------------------------------------

__global__ __launch_bounds__(256) void agg2_kernel(
        const unsigned short* __restrict__ h2,
        const float* __restrict__ als2, const float* __restrict__ ald2,
        const int* __restrict__ deg, const int* __restrict__ csr_src,
        const int* __restrict__ ocnt, const int* __restrict__ oflow,
        const float* __restrict__ b2, unsigned short* __restrict__ y2) {
    agg_body<H2, 2, true, true, false, true, true>(
        blockIdx.x * 4 + (threadIdx.x >> 6), threadIdx.x & 63,
        h2, als2, ald2, deg, csr_src, ocnt, oflow, b2, y2);
}

__global__ __launch_bounds__(256) void agg3_kernel(
        const float* __restrict__ h3,
        const float* __restrict__ als3, const float* __restrict__ ald3,
        const int* __restrict__ deg, const int* __restrict__ csr_src,
        const int* __restrict__ ocnt, const int* __restrict__ oflow,
        const float* __restrict__ b3, float* __restrict__ out) {
    agg_body<N_CLS, 1, true, false, true, false, false>(
        blockIdx.x * 4 + (threadIdx.x >> 6), threadIdx.x & 63,
        h3, als3, ald3, deg, csr_src, ocnt, oflow, b3, out);
}

// ---------------- launch ----------------

extern "C" void kernel_launch(void* const* d_in, const int* in_sizes, int n_in,
                              void* d_out, int out_size, void* d_ws, size_t ws_size,
                              hipStream_t stream) {
    const float* x   = (const float*)d_in[0];
    const int*   ei  = (const int*)d_in[1];
    const float* W1  = (const float*)d_in[2];
    const float* a1s = (const float*)d_in[3];
    const float* a1d = (const float*)d_in[4];
    const float* b1  = (const float*)d_in[5];
    const float* W2  = (const float*)d_in[6];
    const float* a2s = (const float*)d_in[7];
    const float* a2d = (const float*)d_in[8];
    const float* b2  = (const float*)d_in[9];
    const float* W3  = (const float*)d_in[10];
    const float* a3s = (const float*)d_in[11];
    const float* a3d = (const float*)d_in[12];
    const float* b3  = (const float*)d_in[13];
    float* out = (float*)d_out;

    char* ws = (char*)d_ws;
    size_t off = 0;
    auto alloc = [&](size_t bytes) {
        void* p = ws + off;
        off = (off + bytes + 255) & ~(size_t)255;
        return p;
    };
    int*            deg      = (int*)alloc(N_NODES * 4);
    int*            ocnt     = (int*)alloc(4);
    int*            oflow    = (int*)alloc(2 * 8192 * 4);
    int*            csr_src  = (int*)alloc((size_t)N_NODES * DEGMAX * 4);  // 5.1 MB
    float*          alph     = (float*)alloc((size_t)6 * N_NODES * 4);
    float*          wab      = (float*)alloc(1792 * 4);
    unsigned short* xb       = (unsigned short*)alloc((size_t)N_NODES * F_IN * 2);
    unsigned short* w1t      = (unsigned short*)alloc((size_t)H1 * F_IN * 2);
    unsigned short* w2t      = (unsigned short*)alloc((size_t)H2 * H1 * 2);
    unsigned short* w3t      = (unsigned short*)alloc((size_t)N_CLS * H2 * 2);
    unsigned short* zb       = (unsigned short*)alloc((size_t)N_NODES * F_IN * 2);  // agg(x)
    unsigned short* y1       = (unsigned short*)alloc((size_t)N_NODES * H1 * 2);    // L1 out / L2-agg out (aliased)
    unsigned short* h2       = (unsigned short*)alloc((size_t)N_NODES * H2 * 2);
    float*          h3       = (float*)alloc((size_t)N_NODES * N_CLS * 4);
    (void)alloc(128 * 1024);  // slack

    unsigned short* y2 = y1;  // y1 fully consumed before y2 is produced

    float* als1 = alph + 0 * N_NODES; float* ald1 = alph + 1 * N_NODES;
    float* als2 = alph + 2 * N_NODES; float* ald2 = alph + 3 * N_NODES;
    float* als3 = alph + 4 * N_NODES; float* ald3 = alph + 5 * N_NODES;

    dim3 blk(256);
    const int mt128 = (N_NODES + 127) / 128;       // 157
    const int mt64  = (N_NODES + 63) / 64;         // 313

    // 1. minimal prep: zero deg/ocnt + W1 wa vectors (critical path only)
    prep0_kernel<<<PZ + PW1, blk, 0, stream>>>(
        W1, a1s, a1d, W2, a2s, a2d, W3, a3s, a3d, wab, deg, ocnt);
    // 2. bucket-CSR fill + castX tail + gemv-L1 tail
    fill_castx_gemv1_kernel<<<CB_CNT + CXB + NODEB, blk, 0, stream>>>(
        ei, deg, csr_src, ocnt, oflow, x, xb, wab, als1, ald1);
    // 3. layer-1 aggregation (input space) + castT-all tail + remaining wa tail
    agg1_tails_kernel<<<NODEB + CTB + 192, blk, 0, stream>>>(
        xb, als1, ald1, deg, csr_src, ocnt, oflow, zb,
        W1, w1t, W2, w2t, W3, w3t, a1s, a1d, a2s, a2d, a3s, a3d, wab);
    // 4. layer-1 GEMM: y1 = relu(zb @ W1 + b1)
    gemm_fused<128, 8, true, true, 0, false><<<8 * mt128, blk, 0, stream>>>(
        zb, w1t, y1, b1, N_NODES, F_IN, H1, 8 * mt128,
        nullptr, nullptr, nullptr, nullptr, nullptr);
    // 5. layer-2 GEMM (h2 = y1 @ W2) + gemv-L2 tail (als2 from y1)
    gemm_fused<128, 4, false, true, H1, true><<<4 * mt128 + NODEB, blk, 0, stream>>>(
        y1, w2t, h2, nullptr, N_NODES, H1, H2, 4 * mt128,
        y1, wab + 256, wab + 768, als2, ald2);
    // 6. layer-2 aggregation (2 waves/node): y2 = relu(agg(h2) + b2)
    agg2_kernel<<<2 * NODEB, blk, 0, stream>>>(
        h2, als2, ald2, deg, csr_src, ocnt, oflow, b2, y2);
    // 7. layer-3 GEMM (h3 = y2 @ W3) + gemv-L3 tail (als3 from y2)
    gemm_fused<64, 1, false, false, H2, true><<<mt64 + NODEB, blk, 0, stream>>>(
        y2, w3t, h3, nullptr, N_NODES, H2, N_CLS, mt64,
        y2, wab + 1280, wab + 1536, als3, ald3);
    // 8. layer-3 aggregation + bias + log_softmax
    agg3_kernel<<<NODEB, blk, 0, stream>>>(
        h3, als3, ald3, deg, csr_src, ocnt, oflow, b3, out);
}

// Round 12
// 215.265 us; speedup vs baseline: 1.0052x; 1.0052x over previous
//
#include <hip/hip_runtime.h>
#include <math.h>

#define N_NODES 20000
#define N_EDGESC 320000
#define ET (N_EDGESC + N_NODES)   // 340000 incl. self-loops
#define F_IN 128
#define H1 512
#define H2 256
#define N_CLS 40
#define NEG_SLOPE 0.2f
#define DEGMAX 64                 // slot capacity; overflow list handles deg>64

typedef __attribute__((ext_vector_type(8))) short short8;
typedef __attribute__((ext_vector_type(4))) float floatx4;

__device__ __forceinline__ unsigned short f2bf(float x) {
    unsigned u = __float_as_uint(x);
    unsigned r = (u + 0x7fffu + ((u >> 16) & 1u)) >> 16;  // RNE
    return (unsigned short)r;
}
__device__ __forceinline__ float bflo(unsigned v) { return __uint_as_float(v << 16); }
__device__ __forceinline__ float bfhi(unsigned v) { return __uint_as_float(v & 0xffff0000u); }
__device__ __forceinline__ float bf1(unsigned short v) { return __uint_as_float((unsigned)v << 16); }
__device__ __forceinline__ float leaky(float e) { return (e > 0.f) ? e : e * NEG_SLOPE; }

// ---------------- gemv body: als[i]=in[i,:].wvs, ald[i]=in[i,:].wvd --------
template <int DIN, bool IN_BF16>
__device__ __forceinline__ void gemv2_body(int node, int lane, const void* __restrict__ in,
                                           const float* __restrict__ wvs,
                                           const float* __restrict__ wvd,
                                           float* __restrict__ als, float* __restrict__ ald) {
    constexpr int C = DIN / 64;
    float ss = 0.f, sd = 0.f;
    if constexpr (IN_BF16) {
        const unsigned short* r = (const unsigned short*)in + (size_t)node * DIN + lane * C;
        float f[C];
        if constexpr (C == 8) {
            uint4 v = *(const uint4*)r;
            f[0] = bflo(v.x); f[1] = bfhi(v.x); f[2] = bflo(v.y); f[3] = bfhi(v.y);
            f[4] = bflo(v.z); f[5] = bfhi(v.z); f[6] = bflo(v.w); f[7] = bfhi(v.w);
        } else {
            uint2 v = *(const uint2*)r;
            f[0] = bflo(v.x); f[1] = bfhi(v.x); f[2] = bflo(v.y); f[3] = bfhi(v.y);
        }
        #pragma unroll
        for (int c = 0; c < C; ++c) {
            ss += f[c] * wvs[lane * C + c];
            sd += f[c] * wvd[lane * C + c];
        }
    } else {
        const float* r = (const float*)in + (size_t)node * DIN + lane * 2;
        float2 v = *(const float2*)r;
        ss = v.x * wvs[lane * 2] + v.y * wvs[lane * 2 + 1];
        sd = v.x * wvd[lane * 2] + v.y * wvd[lane * 2 + 1];
    }
    #pragma unroll
    for (int off = 32; off; off >>= 1) {
        ss += __shfl_xor(ss, off);
        sd += __shfl_xor(sd, off);
    }
    if (lane == 0) { als[node] = ss; ald[node] = sd; }
}

// ---------------- prep: cast x, W^T casts, wa GEMVs, zero deg+ocnt ---------
#define NCT (F_IN * H1 + H1 * H2 + H2 * N_CLS)  // 206848
#define PB_CASTX 2500
#define PB_CASTT ((NCT + 255) / 256)             // 808
#define PB_WA 224
#define PB_ZERO ((N_NODES + 1 + 255) / 256)      // deg + ocnt

__global__ __launch_bounds__(256) void prep_kernel(
        const float* __restrict__ x, unsigned short* __restrict__ xb,
        const float* __restrict__ W1, unsigned short* __restrict__ w1t,
        const float* __restrict__ a1s, const float* __restrict__ a1d,
        const float* __restrict__ W2, unsigned short* __restrict__ w2t,
        const float* __restrict__ a2s, const float* __restrict__ a2d,
        const float* __restrict__ W3, unsigned short* __restrict__ w3t,
        const float* __restrict__ a3s, const float* __restrict__ a3d,
        float* __restrict__ wab, int* __restrict__ deg, int* __restrict__ ocnt) {
    int bid = blockIdx.x, t = threadIdx.x;
    if (bid < PB_CASTX) {
        int i = (bid * 256 + t) * 4;
        float4 v = *(const float4*)(x + i);
        ushort4 o = { f2bf(v.x), f2bf(v.y), f2bf(v.z), f2bf(v.w) };
        *(ushort4*)(xb + i) = o;
    } else if (bid < PB_CASTX + PB_CASTT) {
        int i = (bid - PB_CASTX) * 256 + t;
        if (i < F_IN * H1) {
            int k = i >> 9, n = i & 511;
            w1t[n * F_IN + k] = f2bf(W1[i]);
        } else if (i < F_IN * H1 + H1 * H2) {
            int j = i - F_IN * H1;
            int k = j >> 8, n = j & 255;
            w2t[n * H1 + k] = f2bf(W2[j]);
        } else if (i < NCT) {
            int j = i - (F_IN * H1 + H1 * H2);
            int k = j / N_CLS, n = j - k * N_CLS;
            w3t[n * H2 + k] = f2bf(W3[j]);
        }
    } else if (bid < PB_CASTX + PB_CASTT + PB_WA) {
        int lane = t & 63;
        int row = (bid - PB_CASTX - PB_CASTT) * 4 + (t >> 6);  // 0..895
        const float *W, *vs, *vd;
        float *os, *od;
        int N, k;
        if (row < 128)      { k = row;       W = W1; vs = a1s; vd = a1d; os = wab;        od = wab + 128;  N = H1; }
        else if (row < 640) { k = row - 128; W = W2; vs = a2s; vd = a2d; os = wab + 256;  od = wab + 768;  N = H2; }
        else                { k = row - 640; W = W3; vs = a3s; vd = a3d; os = wab + 1280; od = wab + 1536; N = N_CLS; }
        const float* r = W + (size_t)k * N;
        float ss = 0.f, sd = 0.f;
        for (int n = lane; n < N; n += 64) {
            float v = r[n];
            ss += v * vs[n];
            sd += v * vd[n];
        }
        #pragma unroll
        for (int off = 32; off; off >>= 1) {
            ss += __shfl_xor(ss, off);
            sd += __shfl_xor(sd, off);
        }
        if (lane == 0) { os[k] = ss; od[k] = sd; }
    } else {
        int i = (bid - PB_CASTX - PB_CASTT - PB_WA) * 256 + t;
        if (i < N_NODES) deg[i] = 0;
        else if (i == N_NODES) *ocnt = 0;
    }
}

// ---------------- bucket-CSR fill (2 edges/thread) + gemv-L1 tail ----------
#define CB_CNT ((ET / 2 + 255) / 256)  // 665

__global__ __launch_bounds__(256) void fill_gemv1_kernel(
        const int* __restrict__ ei, int* __restrict__ deg,
        int* __restrict__ csr_src, int* __restrict__ ocnt, int* __restrict__ oflow,
        const float* __restrict__ x, const float* __restrict__ wab,
        float* __restrict__ als1, float* __restrict__ ald1) {
    int bid = blockIdx.x, t = threadIdx.x;
    if (bid < CB_CNT) {
        int e0 = (bid * 256 + t) * 2;
        if (e0 >= ET) return;
        int s0, d0, s1, d1;
        if (e0 < N_EDGESC) {  // pairs never straddle (both even boundaries)
            int2 ss = *(const int2*)(ei + e0);
            int2 dd = *(const int2*)(ei + N_EDGESC + e0);
            s0 = ss.x; s1 = ss.y; d0 = dd.x; d1 = dd.y;
        } else {
            s0 = d0 = e0 - N_EDGESC;
            s1 = d1 = e0 + 1 - N_EDGESC;
        }
        int slot = atomicAdd(&deg[d0], 1);
        if (slot < DEGMAX) csr_src[(d0 << 6) + slot] = s0;
        else {
            int o = atomicAdd(ocnt, 1);
            oflow[2 * o] = d0; oflow[2 * o + 1] = s0;
        }
        if (e0 + 1 < ET) {
            slot = atomicAdd(&deg[d1], 1);
            if (slot < DEGMAX) csr_src[(d1 << 6) + slot] = s1;
            else {
                int o = atomicAdd(ocnt, 1);
                oflow[2 * o] = d1; oflow[2 * o + 1] = s1;
            }
        }
    } else {
        int node = (bid - CB_CNT) * 4 + (t >> 6);
        if (node < N_NODES)
            gemv2_body<F_IN, false>(node, t & 63, x, wab, wab + 128, als1, ald1);
    }
}

// ---------------- softmax-attention aggregation (bucket CSR) ---------------
// ALPHA3: o3s[node]=out_row.wv3s, o3d likewise (fused next-layer alpha dots).
template <int DOUT, bool BIAS, bool RELU, bool LSM, bool IN_BF16, bool OUT_BF16, bool ALPHA3>
__global__ __launch_bounds__(256) void agg_kernel(const void* __restrict__ h,
                                                  const float* __restrict__ as,
                                                  const float* __restrict__ ad,
                                                  const int* __restrict__ deg,
                                                  const int* __restrict__ csr_src,
                                                  const int* __restrict__ ocnt,
                                                  const int* __restrict__ oflow,
                                                  const float* __restrict__ bias,
                                                  void* __restrict__ outp,
                                                  const float* __restrict__ wv3s,
                                                  const float* __restrict__ wv3d,
                                                  float* __restrict__ o3s,
                                                  float* __restrict__ o3d) {
    constexpr int C = (DOUT + 63) / 64;
    int wave = threadIdx.x >> 6, lane = threadIdx.x & 63;
    int node = blockIdx.x * 4 + wave;
    if (node >= N_NODES) return;
    int degt = deg[node];
    int cnt = min(degt, DEGMAX);
    int base = node << 6;
    float adi = ad[node];
    bool ovf = degt > DEGMAX;          // ~never
    int novf = ovf ? *ocnt : 0;

    bool has0 = lane < cnt;
    int sj = has0 ? csr_src[base + lane] : 0;
    float ej = has0 ? leaky(as[sj] + adi) : -INFINITY;

    float m = ej;
    if (ovf) {
        for (int i = lane; i < novf; i += 64)
            if (oflow[2 * i] == node) m = fmaxf(m, leaky(as[oflow[2 * i + 1]] + adi));
    }
    #pragma unroll
    for (int off = 32; off; off >>= 1) m = fmaxf(m, __shfl_xor(m, off));

    float den = has0 ? expf(ej - m) : 0.f;
    if (ovf) {
        for (int i = lane; i < novf; i += 64)
            if (oflow[2 * i] == node) den += expf(leaky(as[oflow[2 * i + 1]] + adi) - m);
    }
    #pragma unroll
    for (int off = 32; off; off >>= 1) den += __shfl_xor(den, off);
    float invden = 1.f / den;

    float wgt = has0 ? expf(ej - m) * invden : 0.f;

    float acc[C];
    #pragma unroll
    for (int c = 0; c < C; ++c) acc[c] = 0.f;

    auto fetch = [&](int s, float* f) {
        if constexpr (IN_BF16) {
            const unsigned short* hr = (const unsigned short*)h + (size_t)s * DOUT + lane * C;
            if constexpr (C == 8) {
                uint4 v = *(const uint4*)hr;
                f[0] = bflo(v.x); f[1] = bfhi(v.x); f[2] = bflo(v.y); f[3] = bfhi(v.y);
                f[4] = bflo(v.z); f[5] = bfhi(v.z); f[6] = bflo(v.w); f[7] = bfhi(v.w);
            } else if constexpr (C == 4) {
                uint2 v = *(const uint2*)hr;
                f[0] = bflo(v.x); f[1] = bfhi(v.x); f[2] = bflo(v.y); f[3] = bfhi(v.y);
            } else if constexpr (C == 2) {
                unsigned v = *(const unsigned*)hr;
                f[0] = bflo(v); f[1] = bfhi(v);
            } else {  // C == 1, DOUT may be < 64
                if (lane < DOUT)
                    f[0] = bf1(((const unsigned short*)h)[(size_t)s * DOUT + lane]);
                else f[0] = 0.f;
            }
        } else {
            if (lane < DOUT) f[0] = ((const float*)h)[(size_t)s * DOUT + lane];
            else f[0] = 0.f;
        }
    };

    int j = 0;
    for (; j + 7 < cnt; j += 8) {
        int s[8]; float a[8]; float f[8][C];
        #pragma unroll
        for (int u = 0; u < 8; ++u) { s[u] = __shfl(sj, j + u); a[u] = __shfl(wgt, j + u); }
        #pragma unroll
        for (int u = 0; u < 8; ++u) fetch(s[u], f[u]);
        #pragma unroll
        for (int u = 0; u < 8; ++u)
            #pragma unroll
            for (int c = 0; c < C; ++c) acc[c] += a[u] * f[u][c];
    }
    for (; j < cnt; ++j) {
        int s0 = __shfl(sj, j);
        float a0 = __shfl(wgt, j);
        float f0[C];
        fetch(s0, f0);
        #pragma unroll
        for (int c = 0; c < C; ++c) acc[c] += a0 * f0[c];
    }
    if (ovf) {  // wave-uniform scan of the (tiny) overflow list
        for (int i = 0; i < novf; ++i) {
            if (oflow[2 * i] == node) {
                int s0 = oflow[2 * i + 1];
                float a0 = expf(leaky(as[s0] + adi) - m) * invden;
                float f0[C];
                fetch(s0, f0);
                #pragma unroll
                for (int c = 0; c < C; ++c) acc[c] += a0 * f0[c];
            }
        }
    }

    if constexpr (!LSM) {
        float ps = 0.f, pd = 0.f;
        #pragma unroll
        for (int c = 0; c < C; ++c) {
            int col = lane * C + c;
            if (DOUT % 64 == 0 || col < DOUT) {
                float v = acc[c];
                if constexpr (BIAS) v += bias[col];
                if constexpr (RELU) v = fmaxf(v, 0.f);
                if constexpr (ALPHA3) { ps += v * wv3s[col]; pd += v * wv3d[col]; }
                if constexpr (OUT_BF16)
                    ((unsigned short*)outp)[(size_t)node * DOUT + col] = f2bf(v);
                else
                    ((float*)outp)[(size_t)node * DOUT + col] = v;
            }
        }
        if constexpr (ALPHA3) {
            #pragma unroll
            for (int off = 32; off; off >>= 1) {
                ps += __shfl_xor(ps, off);
                pd += __shfl_xor(pd, off);
            }
            if (lane == 0) { o3s[node] = ps; o3d[node] = pd; }
        }
    } else {
        float v = (lane < DOUT) ? (acc[0] + bias[lane]) : -INFINITY;
        float mm = v;
        #pragma unroll
        for (int off = 32; off; off >>= 1) mm = fmaxf(mm, __shfl_xor(mm, off));
        float ex = (lane < DOUT) ? expf(v - mm) : 0.f;
        float Z = ex;
        #pragma unroll
        for (int off = 32; off; off >>= 1) Z += __shfl_xor(Z, off);
        if (lane < DOUT) ((float*)outp)[(size_t)node * DOUT + lane] = v - mm - logf(Z);
    }
}

// ---------------- MFMA GEMM (1D grid) + optional tail gemv -----------------
// OUT_BF16 && NT>1: LDS-repacked uint4 stores. OUT_BF16 && NT==1 (N<64):
// direct scalar bf16 stores. else: fp32 scalar stores.
#define LDT 40   // padded LDS stride (bf16) per 32-wide k tile
#define LSO 66   // epilogue repack stride (bf16)

template <int MT, int NT, bool BIASRELU, bool OUT_BF16, int GDIN, bool GBF16>
__global__ __launch_bounds__(256) void gemm_fused(
        const unsigned short* __restrict__ A, const unsigned short* __restrict__ Bt,
        void* __restrict__ Cp, const float* __restrict__ bias,
        int M, int K, int N, int gemm_blocks,
        const void* __restrict__ gin, const float* __restrict__ wvs,
        const float* __restrict__ wvd, float* __restrict__ als, float* __restrict__ ald) {
    constexpr int MI = MT / 64;
    __shared__ unsigned short As[MT * LDT];
    __shared__ unsigned short Bs[64 * LDT];
    __shared__ unsigned short Ls[64 * LSO];
    int bid = blockIdx.x, t = threadIdx.x;
    int w = t >> 6, lane = t & 63;

    if (bid >= gemm_blocks) {
        if constexpr (GDIN > 0) {
            int node = (bid - gemm_blocks) * 4 + w;
            if (node < N_NODES)
                gemv2_body<GDIN, GBF16>(node, lane, gin, wvs, wvd, als, ald);
        }
        return;
    }

    int quad = lane >> 4, l16 = lane & 15;
    int bm = (bid / NT) * MT, bn = (bid % NT) * 64;
    int ar0 = t >> 2;
    int ak = (t & 3) * 8;

    floatx4 acc[MI][4];
    #pragma unroll
    for (int i = 0; i < MI; ++i)
        #pragma unroll
        for (int j = 0; j < 4; ++j) acc[i][j] = (floatx4){0.f, 0.f, 0.f, 0.f};

    uint4 pa0 = {0,0,0,0}, pa1 = {0,0,0,0}, pb = {0,0,0,0};
    {
        int gm0 = bm + ar0, gn = bn + ar0;
        if (gm0 < M) pa0 = *(const uint4*)(A + (size_t)gm0 * K + ak);
        if constexpr (MI == 2) {
            int gm1 = bm + 64 + ar0;
            if (gm1 < M) pa1 = *(const uint4*)(A + (size_t)gm1 * K + ak);
        }
        if (gn < N) pb = *(const uint4*)(Bt + (size_t)gn * K + ak);
    }

    for (int k0 = 0; k0 < K; k0 += 32) {
        *(uint4*)(&As[ar0 * LDT + ak]) = pa0;
        if constexpr (MI == 2) *(uint4*)(&As[(64 + ar0) * LDT + ak]) = pa1;
        *(uint4*)(&Bs[ar0 * LDT + ak]) = pb;
        __syncthreads();

        int kn = k0 + 32;
        if (kn < K) {
            int gm0 = bm + ar0, gn = bn + ar0;
            pa0 = (gm0 < M) ? *(const uint4*)(A + (size_t)gm0 * K + kn + ak) : (uint4){0,0,0,0};
            if constexpr (MI == 2) {
                int gm1 = bm + 64 + ar0;
                pa1 = (gm1 < M) ? *(const uint4*)(A + (size_t)gm1 * K + kn + ak) : (uint4){0,0,0,0};
            }
            pb = (gn < N) ? *(const uint4*)(Bt + (size_t)gn * K + kn + ak) : (uint4){0,0,0,0};
        }

        short8 a[MI], b[4];
        #pragma unroll
        for (int mi = 0; mi < MI; ++mi)
            a[mi] = *(short8*)(&As[(w * (MT / 4) + mi * 16 + l16) * LDT + quad * 8]);
        #pragma unroll
        for (int ni = 0; ni < 4; ++ni)
            b[ni] = *(short8*)(&Bs[(ni * 16 + l16) * LDT + quad * 8]);
        #pragma unroll
        for (int mi = 0; mi < MI; ++mi)
            #pragma unroll
            for (int ni = 0; ni < 4; ++ni)
                acc[mi][ni] = __builtin_amdgcn_mfma_f32_16x16x32_bf16(a[mi], b[ni], acc[mi][ni], 0, 0, 0);
        __syncthreads();
    }

    if constexpr (OUT_BF16 && NT == 1) {
        // direct scalar bf16 stores (N < 64)
        #pragma unroll
        for (int mi = 0; mi < MI; ++mi) {
            #pragma unroll
            for (int r = 0; r < 4; ++r) {
                int row = bm + w * (MT / 4) + mi * 16 + quad * 4 + r;
                if (row >= M) continue;
                #pragma unroll
                for (int ni = 0; ni < 4; ++ni) {
                    int col = bn + ni * 16 + l16;
                    float v = acc[mi][ni][r];
                    if constexpr (BIASRELU) v = fmaxf(v + bias[col], 0.f);
                    if (col < N) ((unsigned short*)Cp)[(size_t)row * N + col] = f2bf(v);
                }
            }
        }
    } else if constexpr (OUT_BF16) {
        #pragma unroll
        for (int mi = 0; mi < MI; ++mi) {
            #pragma unroll
            for (int ni = 0; ni < 4; ++ni) {
                int col = bn + ni * 16 + l16;
                #pragma unroll
                for (int r = 0; r < 4; ++r) {
                    float v = acc[mi][ni][r];
                    if constexpr (BIASRELU) v = fmaxf(v + bias[col], 0.f);
                    Ls[(w * 16 + quad * 4 + r) * LSO + ni * 16 + l16] = f2bf(v);
                }
            }
            __syncthreads();
            #pragma unroll
            for (int i = 0; i < 2; ++i) {
                int idx = t + i * 256;
                int lrow = idx >> 3, c8 = (idx & 7) * 8;
                int grow = bm + (lrow >> 4) * (MT / 4) + mi * 16 + (lrow & 15);
                if (grow < M)
                    *(uint4*)((unsigned short*)Cp + (size_t)grow * N + bn + c8) =
                        *(uint4*)(&Ls[lrow * LSO + c8]);
            }
            __syncthreads();
        }
    } else {
        #pragma unroll
        for (int mi = 0; mi < MI; ++mi) {
            #pragma unroll
            for (int r = 0; r < 4; ++r) {
                int row = bm + w * (MT / 4) + mi * 16 + quad * 4 + r;
                if (row >= M) continue;
                #pragma unroll
                for (int ni = 0; ni < 4; ++ni) {
                    int col = bn + ni * 16 + l16;
                    if (col < N) ((float*)Cp)[(size_t)row * N + col] = acc[mi][ni][r];
                }
            }
        }
    }
}

// ---------------- launch ----------------

extern "C" void kernel_launch(void* const* d_in, const int* in_sizes, int n_in,
                              void* d_out, int out_size, void* d_ws, size_t ws_size,
                              hipStream_t stream) {
    const float* x   = (const float*)d_in[0];
    const int*   ei  = (const int*)d_in[1];
    const float* W1  = (const float*)d_in[2];
    const float* a1s = (const float*)d_in[3];
    const float* a1d = (const float*)d_in[4];
    const float* b1  = (const float*)d_in[5];
    const float* W2  = (const float*)d_in[6];
    const float* a2s = (const float*)d_in[7];
    const float* a2d = (const float*)d_in[8];
    const float* b2  = (const float*)d_in[9];
    const float* W3  = (const float*)d_in[10];
    const float* a3s = (const float*)d_in[11];
    const float* a3d = (const float*)d_in[12];
    const float* b3  = (const float*)d_in[13];
    float* out = (float*)d_out;

    char* ws = (char*)d_ws;
    size_t off = 0;
    auto alloc = [&](size_t bytes) {
        void* p = ws + off;
        off = (off + bytes + 255) & ~(size_t)255;
        return p;
    };
    int*            deg      = (int*)alloc(N_NODES * 4);
    int*            ocnt     = (int*)alloc(4);
    int*            oflow    = (int*)alloc(2 * 8192 * 4);
    int*            csr_src  = (int*)alloc((size_t)N_NODES * DEGMAX * 4);  // 5.1 MB
    float*          alph     = (float*)alloc((size_t)6 * N_NODES * 4);
    float*          wab      = (float*)alloc(1792 * 4);
    unsigned short* xb       = (unsigned short*)alloc((size_t)N_NODES * F_IN * 2);
    unsigned short* w1t      = (unsigned short*)alloc((size_t)H1 * F_IN * 2);
    unsigned short* w2t      = (unsigned short*)alloc((size_t)H2 * H1 * 2);
    unsigned short* w3t      = (unsigned short*)alloc((size_t)N_CLS * H2 * 2);
    unsigned short* zb       = (unsigned short*)alloc((size_t)N_NODES * F_IN * 2);  // agg(x)
    unsigned short* y1       = (unsigned short*)alloc((size_t)N_NODES * H1 * 2);    // L1 out / L2-agg out (aliased)
    unsigned short* h2       = (unsigned short*)alloc((size_t)N_NODES * H2 * 2);
    unsigned short* h3       = (unsigned short*)alloc((size_t)N_NODES * N_CLS * 2); // bf16 final logits
    (void)alloc(128 * 1024);  // slack

    unsigned short* y2 = y1;  // y1 fully consumed before y2 is produced

    float* als1 = alph + 0 * N_NODES; float* ald1 = alph + 1 * N_NODES;
    float* als2 = alph + 2 * N_NODES; float* ald2 = alph + 3 * N_NODES;
    float* als3 = alph + 4 * N_NODES; float* ald3 = alph + 5 * N_NODES;

    dim3 blk(256);
    int nodeblocks = (N_NODES + 3) / 4;            // 5000
    const int mt128 = (N_NODES + 127) / 128;       // 157
    const int mt64  = (N_NODES + 63) / 64;         // 313

    // 1. prep: cast x, W^T casts, wa GEMVs, zero deg/ocnt
    prep_kernel<<<PB_CASTX + PB_CASTT + PB_WA + PB_ZERO, blk, 0, stream>>>(
        x, xb, W1, w1t, a1s, a1d, W2, w2t, a2s, a2d, W3, w3t, a3s, a3d, wab, deg, ocnt);
    // 2. bucket-CSR fill (2 edges/thread) + gemv-L1 tail
    fill_gemv1_kernel<<<CB_CNT + nodeblocks, blk, 0, stream>>>(
        ei, deg, csr_src, ocnt, oflow, x, wab, als1, ald1);
    // 3. layer-1 aggregation in input space (128 cols)
    agg_kernel<F_IN, false, false, false, true, true, false><<<nodeblocks, blk, 0, stream>>>(
        xb, als1, ald1, deg, csr_src, ocnt, oflow, nullptr, zb, nullptr, nullptr, nullptr, nullptr);
    // 4. layer-1 GEMM: y1 = relu(zb @ W1 + b1)
    gemm_fused<128, 8, true, true, 0, false><<<8 * mt128, blk, 0, stream>>>(
        zb, w1t, y1, b1, N_NODES, F_IN, H1, 8 * mt128,
        nullptr, nullptr, nullptr, nullptr, nullptr);
    // 5. layer-2 GEMM (h2 = y1 @ W2) + gemv-L2 tail (als2 from y1)
    gemm_fused<128, 4, false, true, H1, true><<<4 * mt128 + nodeblocks, blk, 0, stream>>>(
        y1, w2t, h2, nullptr, N_NODES, H1, H2, 4 * mt128,
        y1, wab + 256, wab + 768, als2, ald2);
    // 6. layer-2 aggregation: y2 = relu(agg(h2) + b2), fused als3/ald3 (atomic-free)
    agg_kernel<H2, true, true, false, true, true, true><<<nodeblocks, blk, 0, stream>>>(
        h2, als2, ald2, deg, csr_src, ocnt, oflow, b2, y2, wab + 1280, wab + 1536, als3, ald3);
    // 7. layer-3 GEMM: h3 = y2 @ W3 (bf16 out, direct stores)
    gemm_fused<64, 1, false, true, 0, false><<<mt64, blk, 0, stream>>>(
        y2, w3t, h3, nullptr, N_NODES, H2, N_CLS, mt64,
        nullptr, nullptr, nullptr, nullptr, nullptr);
    // 8. layer-3 aggregation (bf16 gather) + bias + log_softmax
    agg_kernel<N_CLS, true, false, true, true, false, false><<<nodeblocks, blk, 0, stream>>>(
        h3, als3, ald3, deg, csr_src, ocnt, oflow, b3, out, nullptr, nullptr, nullptr, nullptr);
}

// Round 13
// 212.125 us; speedup vs baseline: 1.0201x; 1.0148x over previous
//
#include <hip/hip_runtime.h>
#include <math.h>

#define N_NODES 20000
#define N_EDGESC 320000
#define ET (N_EDGESC + N_NODES)   // 340000 incl. self-loops
#define F_IN 128
#define H1 512
#define H2 256
#define N_CLS 40
#define NEG_SLOPE 0.2f
#define DEGMAX 64                 // slot capacity; overflow list handles deg>64

typedef __attribute__((ext_vector_type(8))) short short8;
typedef __attribute__((ext_vector_type(4))) float floatx4;

__device__ __forceinline__ unsigned short f2bf(float x) {
    unsigned u = __float_as_uint(x);
    unsigned r = (u + 0x7fffu + ((u >> 16) & 1u)) >> 16;  // RNE
    return (unsigned short)r;
}
__device__ __forceinline__ float bflo(unsigned v) { return __uint_as_float(v << 16); }
__device__ __forceinline__ float bfhi(unsigned v) { return __uint_as_float(v & 0xffff0000u); }
__device__ __forceinline__ float leaky(float e) { return (e > 0.f) ? e : e * NEG_SLOPE; }

// ---------------- gemv body: als[i]=in[i,:].wvs, ald[i]=in[i,:].wvd --------
template <int DIN, bool IN_BF16>
__device__ __forceinline__ void gemv2_body(int node, int lane, const void* __restrict__ in,
                                           const float* __restrict__ wvs,
                                           const float* __restrict__ wvd,
                                           float* __restrict__ als, float* __restrict__ ald) {
    constexpr int C = DIN / 64;
    float ss = 0.f, sd = 0.f;
    if constexpr (IN_BF16) {
        const unsigned short* r = (const unsigned short*)in + (size_t)node * DIN + lane * C;
        float f[C];
        if constexpr (C == 8) {
            uint4 v = *(const uint4*)r;
            f[0] = bflo(v.x); f[1] = bfhi(v.x); f[2] = bflo(v.y); f[3] = bfhi(v.y);
            f[4] = bflo(v.z); f[5] = bfhi(v.z); f[6] = bflo(v.w); f[7] = bfhi(v.w);
        } else {
            uint2 v = *(const uint2*)r;
            f[0] = bflo(v.x); f[1] = bfhi(v.x); f[2] = bflo(v.y); f[3] = bfhi(v.y);
        }
        #pragma unroll
        for (int c = 0; c < C; ++c) {
            ss += f[c] * wvs[lane * C + c];
            sd += f[c] * wvd[lane * C + c];
        }
    } else {
        const float* r = (const float*)in + (size_t)node * DIN + lane * 2;
        float2 v = *(const float2*)r;
        ss = v.x * wvs[lane * 2] + v.y * wvs[lane * 2 + 1];
        sd = v.x * wvd[lane * 2] + v.y * wvd[lane * 2 + 1];
    }
    #pragma unroll
    for (int off = 32; off; off >>= 1) {
        ss += __shfl_xor(ss, off);
        sd += __shfl_xor(sd, off);
    }
    if (lane == 0) { als[node] = ss; ald[node] = sd; }
}

// ---------------- prep: cast x, W^T casts, wa GEMVs, zero deg+ocnt ---------
#define NCT (F_IN * H1 + H1 * H2 + H2 * N_CLS)  // 206848
#define PB_CASTX 2500
#define PB_CASTT ((NCT + 255) / 256)             // 808
#define PB_WA 224
#define PB_ZERO ((N_NODES + 1 + 255) / 256)      // deg + ocnt

__global__ __launch_bounds__(256) void prep_kernel(
        const float* __restrict__ x, unsigned short* __restrict__ xb,
        const float* __restrict__ W1, unsigned short* __restrict__ w1t,
        const float* __restrict__ a1s, const float* __restrict__ a1d,
        const float* __restrict__ W2, unsigned short* __restrict__ w2t,
        const float* __restrict__ a2s, const float* __restrict__ a2d,
        const float* __restrict__ W3, unsigned short* __restrict__ w3t,
        const float* __restrict__ a3s, const float* __restrict__ a3d,
        float* __restrict__ wab, int* __restrict__ deg, int* __restrict__ ocnt) {
    int bid = blockIdx.x, t = threadIdx.x;
    if (bid < PB_CASTX) {
        int i = (bid * 256 + t) * 4;
        float4 v = *(const float4*)(x + i);
        ushort4 o = { f2bf(v.x), f2bf(v.y), f2bf(v.z), f2bf(v.w) };
        *(ushort4*)(xb + i) = o;
    } else if (bid < PB_CASTX + PB_CASTT) {
        int i = (bid - PB_CASTX) * 256 + t;
        if (i < F_IN * H1) {
            int k = i >> 9, n = i & 511;
            w1t[n * F_IN + k] = f2bf(W1[i]);
        } else if (i < F_IN * H1 + H1 * H2) {
            int j = i - F_IN * H1;
            int k = j >> 8, n = j & 255;
            w2t[n * H1 + k] = f2bf(W2[j]);
        } else if (i < NCT) {
            int j = i - (F_IN * H1 + H1 * H2);
            int k = j / N_CLS, n = j - k * N_CLS;
            w3t[n * H2 + k] = f2bf(W3[j]);
        }
    } else if (bid < PB_CASTX + PB_CASTT + PB_WA) {
        int lane = t & 63;
        int row = (bid - PB_CASTX - PB_CASTT) * 4 + (t >> 6);  // 0..895
        const float *W, *vs, *vd;
        float *os, *od;
        int N, k;
        if (row < 128)      { k = row;       W = W1; vs = a1s; vd = a1d; os = wab;        od = wab + 128;  N = H1; }
        else if (row < 640) { k = row - 128; W = W2; vs = a2s; vd = a2d; os = wab + 256;  od = wab + 768;  N = H2; }
        else                { k = row - 640; W = W3; vs = a3s; vd = a3d; os = wab + 1280; od = wab + 1536; N = N_CLS; }
        const float* r = W + (size_t)k * N;
        float ss = 0.f, sd = 0.f;
        for (int n = lane; n < N; n += 64) {
            float v = r[n];
            ss += v * vs[n];
            sd += v * vd[n];
        }
        #pragma unroll
        for (int off = 32; off; off >>= 1) {
            ss += __shfl_xor(ss, off);
            sd += __shfl_xor(sd, off);
        }
        if (lane == 0) { os[k] = ss; od[k] = sd; }
    } else {
        int i = (bid - PB_CASTX - PB_CASTT - PB_WA) * 256 + t;
        if (i < N_NODES) deg[i] = 0;
        else if (i == N_NODES) *ocnt = 0;
    }
}

// ---------------- bucket-CSR fill (one pass) + gemv-L1 tail ----------------
#define CB_CNT ((ET + 255) / 256)  // 1329

__global__ __launch_bounds__(256) void fill_gemv1_kernel(
        const int* __restrict__ ei, int* __restrict__ deg,
        int* __restrict__ csr_src, int* __restrict__ ocnt, int* __restrict__ oflow,
        const float* __restrict__ x, const float* __restrict__ wab,
        float* __restrict__ als1, float* __restrict__ ald1) {
    int bid = blockIdx.x, t = threadIdx.x;
    if (bid < CB_CNT) {
        int e = bid * 256 + t;
        if (e < ET) {
            int s, d;
            if (e < N_EDGESC) { s = ei[e]; d = ei[N_EDGESC + e]; }
            else { s = d = e - N_EDGESC; }
            int slot = atomicAdd(&deg[d], 1);
            if (slot < DEGMAX) csr_src[(d << 6) + slot] = s;
            else {
                int o = atomicAdd(ocnt, 1);
                oflow[2 * o] = d;
                oflow[2 * o + 1] = s;
            }
        }
    } else {
        int node = (bid - CB_CNT) * 4 + (t >> 6);
        if (node < N_NODES)
            gemv2_body<F_IN, false>(node, t & 63, x, wab, wab + 128, als1, ald1);
    }
}

// ---------------- softmax-attention aggregation (bucket CSR) ---------------
// ALPHA3: o3s[node]=out_row.wv3s, o3d likewise (fused next-layer alpha dots).
template <int DOUT, bool BIAS, bool RELU, bool LSM, bool IN_BF16, bool OUT_BF16, bool ALPHA3>
__global__ __launch_bounds__(256) void agg_kernel(const void* __restrict__ h,
                                                  const float* __restrict__ as,
                                                  const float* __restrict__ ad,
                                                  const int* __restrict__ deg,
                                                  const int* __restrict__ csr_src,
                                                  const int* __restrict__ ocnt,
                                                  const int* __restrict__ oflow,
                                                  const float* __restrict__ bias,
                                                  void* __restrict__ outp,
                                                  const float* __restrict__ wv3s,
                                                  const float* __restrict__ wv3d,
                                                  float* __restrict__ o3s,
                                                  float* __restrict__ o3d) {
    constexpr int C = (DOUT + 63) / 64;
    int wave = threadIdx.x >> 6, lane = threadIdx.x & 63;
    int node = blockIdx.x * 4 + wave;
    if (node >= N_NODES) return;
    int degt = deg[node];
    int cnt = min(degt, DEGMAX);
    int base = node << 6;
    float adi = ad[node];
    bool ovf = degt > DEGMAX;          // ~never
    int novf = ovf ? *ocnt : 0;

    bool has0 = lane < cnt;
    int sj = has0 ? csr_src[base + lane] : 0;
    float ej = has0 ? leaky(as[sj] + adi) : -INFINITY;

    float m = ej;
    if (ovf) {
        for (int i = lane; i < novf; i += 64)
            if (oflow[2 * i] == node) m = fmaxf(m, leaky(as[oflow[2 * i + 1]] + adi));
    }
    #pragma unroll
    for (int off = 32; off; off >>= 1) m = fmaxf(m, __shfl_xor(m, off));

    float den = has0 ? expf(ej - m) : 0.f;
    if (ovf) {
        for (int i = lane; i < novf; i += 64)
            if (oflow[2 * i] == node) den += expf(leaky(as[oflow[2 * i + 1]] + adi) - m);
    }
    #pragma unroll
    for (int off = 32; off; off >>= 1) den += __shfl_xor(den, off);
    float invden = 1.f / den;

    float wgt = has0 ? expf(ej - m) * invden : 0.f;

    float acc[C];
    #pragma unroll
    for (int c = 0; c < C; ++c) acc[c] = 0.f;

    auto fetch = [&](int s, float* f) {
        if constexpr (IN_BF16) {
            const unsigned short* hr = (const unsigned short*)h + (size_t)s * DOUT + lane * C;
            if constexpr (C == 8) {
                uint4 v = *(const uint4*)hr;
                f[0] = bflo(v.x); f[1] = bfhi(v.x); f[2] = bflo(v.y); f[3] = bfhi(v.y);
                f[4] = bflo(v.z); f[5] = bfhi(v.z); f[6] = bflo(v.w); f[7] = bfhi(v.w);
            } else if constexpr (C == 4) {
                uint2 v = *(const uint2*)hr;
                f[0] = bflo(v.x); f[1] = bfhi(v.x); f[2] = bflo(v.y); f[3] = bfhi(v.y);
            } else {
                unsigned v = *(const unsigned*)hr;
                f[0] = bflo(v); f[1] = bfhi(v);
            }
        } else {
            if (lane < DOUT) f[0] = ((const float*)h)[(size_t)s * DOUT + lane];
            else f[0] = 0.f;
        }
    };

    int j = 0;
    for (; j + 7 < cnt; j += 8) {
        int s[8]; float a[8]; float f[8][C];
        #pragma unroll
        for (int u = 0; u < 8; ++u) { s[u] = __shfl(sj, j + u); a[u] = __shfl(wgt, j + u); }
        #pragma unroll
        for (int u = 0; u < 8; ++u) fetch(s[u], f[u]);
        #pragma unroll
        for (int u = 0; u < 8; ++u)
            #pragma unroll
            for (int c = 0; c < C; ++c) acc[c] += a[u] * f[u][c];
    }
    for (; j < cnt; ++j) {
        int s0 = __shfl(sj, j);
        float a0 = __shfl(wgt, j);
        float f0[C];
        fetch(s0, f0);
        #pragma unroll
        for (int c = 0; c < C; ++c) acc[c] += a0 * f0[c];
    }
    if (ovf) {  // wave-uniform scan of the (tiny) overflow list
        for (int i = 0; i < novf; ++i) {
            if (oflow[2 * i] == node) {
                int s0 = oflow[2 * i + 1];
                float a0 = expf(leaky(as[s0] + adi) - m) * invden;
                float f0[C];
                fetch(s0, f0);
                #pragma unroll
                for (int c = 0; c < C; ++c) acc[c] += a0 * f0[c];
            }
        }
    }

    if constexpr (!LSM) {
        float ps = 0.f, pd = 0.f;
        #pragma unroll
        for (int c = 0; c < C; ++c) {
            int col = lane * C + c;
            if (DOUT % 64 == 0 || col < DOUT) {
                float v = acc[c];
                if constexpr (BIAS) v += bias[col];
                if constexpr (RELU) v = fmaxf(v, 0.f);
                if constexpr (ALPHA3) { ps += v * wv3s[col]; pd += v * wv3d[col]; }
                if constexpr (OUT_BF16)
                    ((unsigned short*)outp)[(size_t)node * DOUT + col] = f2bf(v);
                else
                    ((float*)outp)[(size_t)node * DOUT + col] = v;
            }
        }
        if constexpr (ALPHA3) {
            #pragma unroll
            for (int off = 32; off; off >>= 1) {
                ps += __shfl_xor(ps, off);
                pd += __shfl_xor(pd, off);
            }
            if (lane == 0) { o3s[node] = ps; o3d[node] = pd; }
        }
    } else {
        float v = (lane < DOUT) ? (acc[0] + bias[lane]) : -INFINITY;
        float mm = v;
        #pragma unroll
        for (int off = 32; off; off >>= 1) mm = fmaxf(mm, __shfl_xor(mm, off));
        float ex = (lane < DOUT) ? expf(v - mm) : 0.f;
        float Z = ex;
        #pragma unroll
        for (int off = 32; off; off >>= 1) Z += __shfl_xor(Z, off);
        if (lane < DOUT) ((float*)outp)[(size_t)node * DOUT + lane] = v - mm - logf(Z);
    }
}

// ---------------- MFMA GEMM (1D grid) + optional tail gemv -----------------
#define LDT 40   // padded LDS stride (bf16) per 32-wide k tile
#define LSO 66   // epilogue repack stride (bf16)

template <int MT, int NT, bool BIASRELU, bool OUT_BF16, int GDIN, bool GBF16>
__global__ __launch_bounds__(256) void gemm_fused(
        const unsigned short* __restrict__ A, const unsigned short* __restrict__ Bt,
        void* __restrict__ Cp, const float* __restrict__ bias,
        int M, int K, int N, int gemm_blocks,
        const void* __restrict__ gin, const float* __restrict__ wvs,
        const float* __restrict__ wvd, float* __restrict__ als, float* __restrict__ ald) {
    constexpr int MI = MT / 64;
    __shared__ unsigned short As[MT * LDT];
    __shared__ unsigned short Bs[64 * LDT];
    __shared__ unsigned short Ls[64 * LSO];
    int bid = blockIdx.x, t = threadIdx.x;
    int w = t >> 6, lane = t & 63;

    if (bid >= gemm_blocks) {
        if constexpr (GDIN > 0) {
            int node = (bid - gemm_blocks) * 4 + w;
            if (node < N_NODES)
                gemv2_body<GDIN, GBF16>(node, lane, gin, wvs, wvd, als, ald);
        }
        return;
    }

    int quad = lane >> 4, l16 = lane & 15;
    int bm = (bid / NT) * MT, bn = (bid % NT) * 64;
    int ar0 = t >> 2;
    int ak = (t & 3) * 8;

    floatx4 acc[MI][4];
    #pragma unroll
    for (int i = 0; i < MI; ++i)
        #pragma unroll
        for (int j = 0; j < 4; ++j) acc[i][j] = (floatx4){0.f, 0.f, 0.f, 0.f};

    uint4 pa0 = {0,0,0,0}, pa1 = {0,0,0,0}, pb = {0,0,0,0};
    {
        int gm0 = bm + ar0, gn = bn + ar0;
        if (gm0 < M) pa0 = *(const uint4*)(A + (size_t)gm0 * K + ak);
        if constexpr (MI == 2) {
            int gm1 = bm + 64 + ar0;
            if (gm1 < M) pa1 = *(const uint4*)(A + (size_t)gm1 * K + ak);
        }
        if (gn < N) pb = *(const uint4*)(Bt + (size_t)gn * K + ak);
    }

    for (int k0 = 0; k0 < K; k0 += 32) {
        *(uint4*)(&As[ar0 * LDT + ak]) = pa0;
        if constexpr (MI == 2) *(uint4*)(&As[(64 + ar0) * LDT + ak]) = pa1;
        *(uint4*)(&Bs[ar0 * LDT + ak]) = pb;
        __syncthreads();

        int kn = k0 + 32;
        if (kn < K) {
            int gm0 = bm + ar0, gn = bn + ar0;
            pa0 = (gm0 < M) ? *(const uint4*)(A + (size_t)gm0 * K + kn + ak) : (uint4){0,0,0,0};
            if constexpr (MI == 2) {
                int gm1 = bm + 64 + ar0;
                pa1 = (gm1 < M) ? *(const uint4*)(A + (size_t)gm1 * K + kn + ak) : (uint4){0,0,0,0};
            }
            pb = (gn < N) ? *(const uint4*)(Bt + (size_t)gn * K + kn + ak) : (uint4){0,0,0,0};
        }

        short8 a[MI], b[4];
        #pragma unroll
        for (int mi = 0; mi < MI; ++mi)
            a[mi] = *(short8*)(&As[(w * (MT / 4) + mi * 16 + l16) * LDT + quad * 8]);
        #pragma unroll
        for (int ni = 0; ni < 4; ++ni)
            b[ni] = *(short8*)(&Bs[(ni * 16 + l16) * LDT + quad * 8]);
        #pragma unroll
        for (int mi = 0; mi < MI; ++mi)
            #pragma unroll
            for (int ni = 0; ni < 4; ++ni)
                acc[mi][ni] = __builtin_amdgcn_mfma_f32_16x16x32_bf16(a[mi], b[ni], acc[mi][ni], 0, 0, 0);
        __syncthreads();
    }

    if constexpr (OUT_BF16) {
        #pragma unroll
        for (int mi = 0; mi < MI; ++mi) {
            #pragma unroll
            for (int ni = 0; ni < 4; ++ni) {
                int col = bn + ni * 16 + l16;
                #pragma unroll
                for (int r = 0; r < 4; ++r) {
                    float v = acc[mi][ni][r];
                    if constexpr (BIASRELU) v = fmaxf(v + bias[col], 0.f);
                    Ls[(w * 16 + quad * 4 + r) * LSO + ni * 16 + l16] = f2bf(v);
                }
            }
            __syncthreads();
            #pragma unroll
            for (int i = 0; i < 2; ++i) {
                int idx = t + i * 256;
                int lrow = idx >> 3, c8 = (idx & 7) * 8;
                int grow = bm + (lrow >> 4) * (MT / 4) + mi * 16 + (lrow & 15);
                if (grow < M)
                    *(uint4*)((unsigned short*)Cp + (size_t)grow * N + bn + c8) =
                        *(uint4*)(&Ls[lrow * LSO + c8]);
            }
            __syncthreads();
        }
    } else {
        #pragma unroll
        for (int mi = 0; mi < MI; ++mi) {
            #pragma unroll
            for (int r = 0; r < 4; ++r) {
                int row = bm + w * (MT / 4) + mi * 16 + quad * 4 + r;
                if (row >= M) continue;
                #pragma unroll
                for (int ni = 0; ni < 4; ++ni) {
                    int col = bn + ni * 16 + l16;
                    if (col < N) ((float*)Cp)[(size_t)row * N + col] = acc[mi][ni][r];
                }
            }
        }
    }
}

// ---------------- launch ----------------

extern "C" void kernel_launch(void* const* d_in, const int* in_sizes, int n_in,
                              void* d_out, int out_size, void* d_ws, size_t ws_size,
                              hipStream_t stream) {
    const float* x   = (const float*)d_in[0];
    const int*   ei  = (const int*)d_in[1];
    const float* W1  = (const float*)d_in[2];
    const float* a1s = (const float*)d_in[3];
    const float* a1d = (const float*)d_in[4];
    const float* b1  = (const float*)d_in[5];
    const float* W2  = (const float*)d_in[6];
    const float* a2s = (const float*)d_in[7];
    const float* a2d = (const float*)d_in[8];
    const float* b2  = (const float*)d_in[9];
    const float* W3  = (const float*)d_in[10];
    const float* a3s = (const float*)d_in[11];
    const float* a3d = (const float*)d_in[12];
    const float* b3  = (const float*)d_in[13];
    float* out = (float*)d_out;

    char* ws = (char*)d_ws;
    size_t off = 0;
    auto alloc = [&](size_t bytes) {
        void* p = ws + off;
        off = (off + bytes + 255) & ~(size_t)255;
        return p;
    };
    int*            deg      = (int*)alloc(N_NODES * 4);
    int*            ocnt     = (int*)alloc(4);
    int*            oflow    = (int*)alloc(2 * 8192 * 4);
    int*            csr_src  = (int*)alloc((size_t)N_NODES * DEGMAX * 4);  // 5.1 MB
    float*          alph     = (float*)alloc((size_t)6 * N_NODES * 4);
    float*          wab      = (float*)alloc(1792 * 4);
    unsigned short* xb       = (unsigned short*)alloc((size_t)N_NODES * F_IN * 2);
    unsigned short* w1t      = (unsigned short*)alloc((size_t)H1 * F_IN * 2);
    unsigned short* w2t      = (unsigned short*)alloc((size_t)H2 * H1 * 2);
    unsigned short* w3t      = (unsigned short*)alloc((size_t)N_CLS * H2 * 2);
    unsigned short* zb       = (unsigned short*)alloc((size_t)N_NODES * F_IN * 2);  // agg(x)
    unsigned short* y1       = (unsigned short*)alloc((size_t)N_NODES * H1 * 2);    // L1 out / L2-agg out (aliased)
    unsigned short* h2       = (unsigned short*)alloc((size_t)N_NODES * H2 * 2);
    float*          h3       = (float*)alloc((size_t)N_NODES * N_CLS * 4);
    (void)alloc(128 * 1024);  // slack

    unsigned short* y2 = y1;  // y1 fully consumed before y2 is produced

    float* als1 = alph + 0 * N_NODES; float* ald1 = alph + 1 * N_NODES;
    float* als2 = alph + 2 * N_NODES; float* ald2 = alph + 3 * N_NODES;
    float* als3 = alph + 4 * N_NODES; float* ald3 = alph + 5 * N_NODES;

    dim3 blk(256);
    int nodeblocks = (N_NODES + 3) / 4;            // 5000
    const int mt128 = (N_NODES + 127) / 128;       // 157
    const int mt64  = (N_NODES + 63) / 64;         // 313

    // 1. prep: cast x, W^T casts, wa GEMVs, zero deg/ocnt
    prep_kernel<<<PB_CASTX + PB_CASTT + PB_WA + PB_ZERO, blk, 0, stream>>>(
        x, xb, W1, w1t, a1s, a1d, W2, w2t, a2s, a2d, W3, w3t, a3s, a3d, wab, deg, ocnt);
    // 2. bucket-CSR fill (single pass; no count/scan) + gemv-L1 tail
    fill_gemv1_kernel<<<CB_CNT + nodeblocks, blk, 0, stream>>>(
        ei, deg, csr_src, ocnt, oflow, x, wab, als1, ald1);
    // 3. layer-1 aggregation in input space (128 cols)
    agg_kernel<F_IN, false, false, false, true, true, false><<<nodeblocks, blk, 0, stream>>>(
        xb, als1, ald1, deg, csr_src, ocnt, oflow, nullptr, zb, nullptr, nullptr, nullptr, nullptr);
    // 4. layer-1 GEMM: y1 = relu(zb @ W1 + b1)
    gemm_fused<128, 8, true, true, 0, false><<<8 * mt128, blk, 0, stream>>>(
        zb, w1t, y1, b1, N_NODES, F_IN, H1, 8 * mt128,
        nullptr, nullptr, nullptr, nullptr, nullptr);
    // 5. layer-2 GEMM (h2 = y1 @ W2) + gemv-L2 tail (als2 from y1)
    gemm_fused<128, 4, false, true, H1, true><<<4 * mt128 + nodeblocks, blk, 0, stream>>>(
        y1, w2t, h2, nullptr, N_NODES, H1, H2, 4 * mt128,
        y1, wab + 256, wab + 768, als2, ald2);
    // 6. layer-2 aggregation: y2 = relu(agg(h2) + b2), fused als3/ald3 (atomic-free)
    agg_kernel<H2, true, true, false, true, true, true><<<nodeblocks, blk, 0, stream>>>(
        h2, als2, ald2, deg, csr_src, ocnt, oflow, b2, y2, wab + 1280, wab + 1536, als3, ald3);
    // 7. layer-3 GEMM: h3 = y2 @ W3 (fp32 out)
    gemm_fused<64, 1, false, false, 0, false><<<mt64, blk, 0, stream>>>(
        y2, w3t, h3, nullptr, N_NODES, H2, N_CLS, mt64,
        nullptr, nullptr, nullptr, nullptr, nullptr);
    // 8. layer-3 aggregation + bias + log_softmax
    agg_kernel<N_CLS, true, false, true, false, false, false><<<nodeblocks, blk, 0, stream>>>(
        h3, als3, ald3, deg, csr_src, ocnt, oflow, b3, out, nullptr, nullptr, nullptr, nullptr);
}